// Round 16
// baseline (999.261 us; speedup 1.0000x reference)
//
#include <hip/hip_runtime.h>
#include <math.h>

typedef unsigned short ushort_t;
typedef unsigned int uint_t;
typedef unsigned long long u64_t;
typedef __attribute__((ext_vector_type(8))) short short8;
typedef __attribute__((ext_vector_type(4))) float f32x4;

#define N_NODES 8192
#define DIM 512
#define KTOT 1024
#define NCOLS 4096
#define BM 64
#define BN 128
#define NTILE (NCOLS / BN)   // 32 column tiles
#define KIT (KTOT / 32)      // 32 k iterations (BK=32)
#define WIMG_USHORTS ((size_t)NTILE * KIT * 4096)
#define MAXLEV_LDS 128

__device__ __forceinline__ float sigm(float x) { return 1.0f / (1.0f + __expf(-x)); }
__device__ __forceinline__ float tanh_fast(float x) {
    float ax = fabsf(x);
    float e = __expf(2.0f * ax);
    float t = 1.0f - 2.0f / (e + 1.0f);
    return copysignf(t, x);
}
__device__ __forceinline__ uint_t packf(float f) {
    uint_t u = __float_as_uint(f);
    uint_t hi = u & 0xffff0000u;
    float r = f - __uint_as_float(hi);
    return hi | (__float_as_uint(r) >> 16);
}
__device__ __forceinline__ float unpackw(uint_t w) {
    return __uint_as_float(w & 0xffff0000u) + __uint_as_float(w << 16);
}
__device__ __forceinline__ uint_t rne16(float f) {
    uint_t u = __float_as_uint(f);
    return (u + 0x7fffu + ((u >> 16) & 1u)) >> 16;
}

// split 8 packed (hi|lo) u32 -> hi-frag / lo-frag short8
__device__ __forceinline__ void fragAB_u32(const uint4 w0, const uint4 w1,
                                           short8& hi8, short8& lo8) {
    union { uint_t w[4]; short8 s; } H, L;
    uint_t u[8] = { w0.x, w0.y, w0.z, w0.w, w1.x, w1.y, w1.z, w1.w };
#pragma unroll
    for (int j = 0; j < 4; ++j) {
        H.w[j] = (u[2 * j + 1] & 0xffff0000u) | (u[2 * j] >> 16);
        L.w[j] = (u[2 * j + 1] << 16) | (u[2 * j] & 0xffffu);
    }
    hi8 = H.s; lo8 = L.s;
}

// split 8 fp32 -> hi-frag (trunc) / lo-frag (residual) short8
__device__ __forceinline__ void fragA_f32(const float4 f0, const float4 f1,
                                          short8& hi8, short8& lo8) {
    union { uint_t w[4]; short8 s; } H, L;
    float f[8] = { f0.x, f0.y, f0.z, f0.w, f1.x, f1.y, f1.z, f1.w };
#pragma unroll
    for (int j = 0; j < 4; ++j) {
        float a = f[2 * j], b = f[2 * j + 1];
        uint_t h0 = __float_as_uint(a) & 0xffff0000u;
        uint_t h1 = __float_as_uint(b) & 0xffff0000u;
        float r0 = a - __uint_as_float(h0);
        float r1 = b - __uint_as_float(h1);
        H.w[j] = h1 | (h0 >> 16);
        L.w[j] = (__float_as_uint(r1) & 0xffff0000u) | (__float_as_uint(r0) >> 16);
    }
    hi8 = H.s; lo8 = L.s;
}

// ---------------------------------------------------------------------------
// Prep: weights -> bf16 (hi plane, RNE), direct-fragment image (verified r8-r15)
// ---------------------------------------------------------------------------
__global__ void __launch_bounds__(256) prep_wimg_kernel(
    const float* __restrict__ Wx_iou_v, const float* __restrict__ Wh_iou_v,
    const float* __restrict__ Wx_f_v,   const float* __restrict__ Wh_f_v,
    const float* __restrict__ Wx_iou_l, const float* __restrict__ Wh_iou_l,
    const float* __restrict__ Wx_f_l,   const float* __restrict__ Wh_f_l,
    ushort_t* __restrict__ Wimg)
{
    __shared__ float T[32][132];   // T[kk][jloc]
    int p = blockIdx.x >> 5, it = blockIdx.x & 31;
    int tid = threadIdx.x;
#pragma unroll
    for (int e = 0; e < 16; ++e) {
        int lin = e * 256 + tid;
        int dloc = lin & 15, kk = (lin >> 4) & 31, q = lin >> 9;
        int d = p * 16 + dloc;
        int qq = q & 3; bool lang = q >= 4;
        int k = it * 32 + kk;
        const float* W; int col, stride;
        if (qq < 3) { col = qq * DIM + d; stride = 3 * DIM;
            W = (k < DIM) ? (lang ? Wx_iou_l : Wx_iou_v) : (lang ? Wh_iou_l : Wh_iou_v); }
        else        { col = d; stride = DIM;
            W = (k < DIM) ? (lang ? Wx_f_l : Wx_f_v) : (lang ? Wh_f_l : Wh_f_v); }
        int kr = (k < DIM) ? k : (k - DIM);
        T[kk][dloc * 8 + q] = W[(size_t)kr * stride + col];
    }
    __syncthreads();
    size_t tilebase = (size_t)blockIdx.x * 4096;
#pragma unroll
    for (int gch = 0; gch < 2; ++gch) {
        int gi = gch * 256 + tid;          // uint4 index 0..511
        int col = gi >> 2, gd = gi & 3;
        uint_t wds[4];
#pragma unroll
        for (int i = 0; i < 4; ++i) {
            uint_t v0 = rne16(T[gd * 8 + 2 * i][col]);
            uint_t v1 = rne16(T[gd * 8 + 2 * i + 1][col]);
            wds[i] = (v1 << 16) | v0;
        }
        *(uint4*)(Wimg + tilebase + (size_t)gi * 8) = make_uint4(wds[0], wds[1], wds[2], wds[3]);
    }
}

__global__ void prep_bias_kernel(
    const float* __restrict__ bx_iou_v, const float* __restrict__ bh_iou_v,
    const float* __restrict__ bx_f_v,   const float* __restrict__ bh_f_v,
    const float* __restrict__ bx_iou_l, const float* __restrict__ bh_iou_l,
    const float* __restrict__ bx_f_l,   const float* __restrict__ bh_f_l,
    float* __restrict__ bias)
{
    int j = blockIdx.x * blockDim.x + threadIdx.x;
    if (j >= NCOLS) return;
    int d = j >> 3, q = j & 7;
    int qq = q & 3;
    bool lang = (q & 4) != 0;
    const float* bx; const float* bh; int col;
    if (qq < 3) { col = qq * DIM + d; bx = lang ? bx_iou_l : bx_iou_v; bh = lang ? bh_iou_l : bh_iou_v; }
    else        { col = d;            bx = lang ? bx_f_l  : bx_f_v;   bh = lang ? bh_f_l  : bh_f_v; }
    bias[j] = bx[col] + bh[col];
}

// ---------------------------------------------------------------------------
// Level computation + counting sort + rowblock tables (BM=64 variant)
// ---------------------------------------------------------------------------
__global__ void __launch_bounds__(1024) levels_sort_kernel(
    const int* __restrict__ parent,
    int* __restrict__ order, int* __restrict__ offsets,
    int* __restrict__ counts, int* __restrict__ cursors,
    int* __restrict__ nlev, int* __restrict__ tilestart,
    int* __restrict__ rbStart)
{
    __shared__ int s_level[N_NODES];
    __shared__ int s_assigned;
    __shared__ int s_maxlev;
    int tid = threadIdx.x;
    int pr[8];
#pragma unroll
    for (int ii = 0; ii < 8; ++ii) {
        int i = tid + ii * 1024;
        pr[ii] = parent[i];
        s_level[i] = -1;
    }
    for (int i = tid; i <= N_NODES; i += 1024) counts[i] = 0;
    if (tid == 0) { s_assigned = 0; s_maxlev = 0; }
    __syncthreads();

    for (int pass = 0; pass <= N_NODES; ++pass) {
        int newly = 0;
#pragma unroll
        for (int ii = 0; ii < 8; ++ii) {
            int i = tid + ii * 1024;
            if (s_level[i] < 0) {
                int p = pr[ii];
                if (p == 0) { s_level[i] = 0; newly++; }
                else { int lp = s_level[p - 1]; if (lp >= 0) { s_level[i] = lp + 1; newly++; } }
            }
        }
        if (newly) atomicAdd(&s_assigned, newly);
        __syncthreads();
        int a = s_assigned;
        if (a >= N_NODES) break;
        __syncthreads();
    }

#pragma unroll
    for (int ii = 0; ii < 8; ++ii) {
        int i = tid + ii * 1024;
        int lv = s_level[i];
        atomicAdd(&counts[lv], 1);
        atomicMax(&s_maxlev, lv);
    }
    __syncthreads();
    if (tid == 0) {
        int nl = s_maxlev + 1;
        nlev[0] = nl;
        int off = 0, toff = 0, rb = 0;
        for (int l = 0; l < nl; ++l) {
            offsets[l] = off; cursors[l] = off;
            tilestart[l] = toff; rbStart[l] = rb;
            int mt = (counts[l] + BM - 1) / BM;
            rb += mt;
            toff += mt * NTILE;
            off += counts[l];
        }
        offsets[nl] = off;
        tilestart[nl] = toff;
        rbStart[nl] = rb;
        nlev[1] = toff;   // total fused tiles
    }
    __syncthreads();
#pragma unroll
    for (int ii = 0; ii < 8; ++ii) {
        int i = tid + ii * 1024;
        int pos = atomicAdd(&cursors[s_level[i]], 1);
        order[pos] = i;
    }
}

// ---------------------------------------------------------------------------
// Fused worker: BM=64, 8 waves (2 row-groups x 4 col-quarters), per-iter
// pair gates, depth-3 A prefetch, split h/c publish, fence-free sc1 dataflow.
// ---------------------------------------------------------------------------
__global__ void __launch_bounds__(512, 2) tree_fused_kernel(
    const float* __restrict__ inputs, const float* __restrict__ type_mask,
    const ushort_t* __restrict__ Wimg, const float* __restrict__ bias,
    const int* __restrict__ order, const int* __restrict__ offsets,
    const int* __restrict__ nlev, const int* __restrict__ parent,
    const int* __restrict__ rbStart,
    int* __restrict__ colCnt, int* __restrict__ cCnt,
    uint_t* __restrict__ hPack, uint_t* __restrict__ cPack,
    float* __restrict__ out)
{
    float* cOut = out;
    float* hOut = out + (size_t)N_NODES * DIM;

    __shared__ float eps[BM * 132];      // 33.8 KB single-pass transpose
    __shared__ int s_node[BM];
    __shared__ int s_par[BM];
    __shared__ float s_tm[BM][2];
    __shared__ int s_rbs[MAXLEV_LDS];
    __shared__ int s_off[MAXLEV_LDS];

    int tid = threadIdx.x;
    int lane = tid & 63, w = tid >> 6;        // w in 0..7
    int wr = w >> 2, wq = w & 3;              // 2 row groups x 4 col quarters
    int l15 = lane & 15, g = lane >> 4;
    int nl = nlev[0];
    int total = nlev[1];

    int nload = nl + 1; if (nload > MAXLEV_LDS) nload = MAXLEV_LDS;
    for (int i = tid; i < nload; i += 512) { s_rbs[i] = rbStart[i]; s_off[i] = offsets[i]; }
    __syncthreads();

    // B fragment base: cols wq*32 + n*16 + l15 (n<2), granule g
    const ushort_t* bLane = Wimg + (size_t)(wq * 32 + l15) * 32 + (size_t)g * 8;

#define LDB(RB, tilebase, itt) { \
    _Pragma("unroll") for (int n_ = 0; n_ < 2; ++n_) \
        RB[n_] = *(const uint4*)(bLane + (size_t)(tilebase + (itt)) * 4096 + n_ * 512); }

#define LDA_H(RA, itrel) { \
    _Pragma("unroll") for (int m_ = 0; m_ < 2; ++m_) { \
        const uint4* p_ = (const uint4*)(aBaseH[m_] + (itrel) * 32 + g * 8); \
        RA[m_][0] = p_[0]; RA[m_][1] = p_[1]; } }

#define LDA_X(RA, itt) { \
    _Pragma("unroll") for (int m_ = 0; m_ < 2; ++m_) { \
        const float4* p_ = (const float4*)(aBaseX[m_] + (itt) * 32 + g * 8); \
        RA[m_][0] = p_[0]; RA[m_][1] = p_[1]; } }

#define COMP_H(RA, RB) { \
    short8 bh_[2]; \
    _Pragma("unroll") for (int n_ = 0; n_ < 2; ++n_) { \
        union { uint4 u; short8 s; } c_; c_.u = RB[n_]; bh_[n_] = c_.s; } \
    _Pragma("unroll") for (int m_ = 0; m_ < 2; ++m_) { \
        short8 ah_, al_; fragAB_u32(RA[m_][0], RA[m_][1], ah_, al_); \
        _Pragma("unroll") for (int n_ = 0; n_ < 2; ++n_) { \
            acc[m_][n_] = __builtin_amdgcn_mfma_f32_16x16x32_bf16(ah_, bh_[n_], acc[m_][n_], 0, 0, 0); \
            acc[m_][n_] = __builtin_amdgcn_mfma_f32_16x16x32_bf16(al_, bh_[n_], acc[m_][n_], 0, 0, 0); } } }

#define COMP_X(RA, RB) { \
    short8 bh_[2]; \
    _Pragma("unroll") for (int n_ = 0; n_ < 2; ++n_) { \
        union { uint4 u; short8 s; } c_; c_.u = RB[n_]; bh_[n_] = c_.s; } \
    _Pragma("unroll") for (int m_ = 0; m_ < 2; ++m_) { \
        short8 ah_, al_; fragA_f32(RA[m_][0], RA[m_][1], ah_, al_); \
        _Pragma("unroll") for (int n_ = 0; n_ < 2; ++n_) { \
            acc[m_][n_] = __builtin_amdgcn_mfma_f32_16x16x32_bf16(ah_, bh_[n_], acc[m_][n_], 0, 0, 0); \
            acc[m_][n_] = __builtin_amdgcn_mfma_f32_16x16x32_bf16(al_, bh_[n_], acc[m_][n_], 0, 0, 0); } } }

// one-round poll of ALL 32 prev-level columns -> 16-bit pair mask
#define POLL16(colPrev, nPrev) { \
    int ok_ = 1; \
    if (lane < 32) { \
        int c_ = __hip_atomic_load(&(colPrev)[lane], __ATOMIC_RELAXED, \
                                   __HIP_MEMORY_SCOPE_AGENT); \
        ok_ = (c_ >= (nPrev)) ? 1 : 0; \
    } \
    uint_t cm_ = (uint_t)(__ballot(ok_) & 0xffffffffu); \
    uint_t pr_ = cm_ & (cm_ >> 1); \
    pmask = 0; \
    _Pragma("unroll") for (int p_ = 0; p_ < 16; ++p_) \
        pmask |= ((pr_ >> (2 * p_)) & 1u) << p_; }

#define GATEI(colPrev, nPrev, itq, slp) { \
    if (!(pmask & (1u << (itq)))) { \
        for (;;) { \
            POLL16(colPrev, nPrev); \
            if (pmask & (1u << (itq))) break; \
            __builtin_amdgcn_s_sleep(slp); \
        } \
        asm volatile("" ::: "memory"); \
    } }

    for (int t = blockIdx.x; t < total; t += gridDim.x) {
        // locate tile in level-ordered list
        int lev = 0;
        while (lev + 1 < nload && s_rbs[lev + 1] * NTILE <= t) ++lev;
        int lt = t - s_rbs[lev] * NTILE;
        int ntile = lt % NTILE;
        int mt = lt / NTILE;
        int start = s_off[lev];
        int cnt = s_off[lev + 1] - start;
        int jc = ntile * BN;
        int r0 = mt * BM;
        int tbx = ntile * KIT;        // Wimg x half: it 0..15
        int tbh = ntile * KIT + 16;   // Wimg h half: it 16..31
        int nPrev = (lev > 0) ? (s_rbs[lev] - s_rbs[lev - 1]) : 0;

        if (tid < BM) {
            int r = r0 + tid;
            int node = (r < cnt) ? order[start + r] : -1;
            s_node[tid] = node;
            int p = (node >= 0) ? parent[node] : 0;
            s_par[tid] = p;
            float t0 = 0.f, t1 = 0.f;
            if (node >= 0) { t0 = type_mask[node * 2]; t1 = type_mask[node * 2 + 1]; }
            s_tm[tid][0] = t0; s_tm[tid][1] = t1;
        }
        __syncthreads();

        f32x4 acc[2][2];
#pragma unroll
        for (int m = 0; m < 2; ++m)
#pragma unroll
            for (int n = 0; n < 2; ++n) acc[m][n] = (f32x4)(0.f);

        // ---- x-GEMM (no dependencies): gathered input rows
        {
            const float* aBaseX[2];
#pragma unroll
            for (int m = 0; m < 2; ++m) {
                int nd = s_node[wr * 32 + m * 16 + l15];
                aBaseX[m] = inputs + (size_t)(nd < 0 ? 0 : nd) * DIM;
            }
            float4 xa0[2][2], xa1[2][2]; uint4 xb0[2], xb1[2];
            LDA_X(xa0, 0); LDB(xb0, tbx, 0);
            LDA_X(xa1, 1); LDB(xb1, tbx, 1);
#pragma unroll
            for (int ii = 0; ii < 8; ++ii) {
                int e = 2 * ii, o = e + 1;
                __builtin_amdgcn_s_setprio(1);
                COMP_X(xa0, xb0);
                __builtin_amdgcn_s_setprio(0);
                if (e + 2 < 16) { LDA_X(xa0, e + 2); LDB(xb0, tbx, e + 2); }
                __builtin_amdgcn_s_setprio(1);
                COMP_X(xa1, xb1);
                __builtin_amdgcn_s_setprio(0);
                if (o + 2 < 16) { LDA_X(xa1, o + 2); LDB(xb1, tbx, o + 2); }
            }
        }

        // ---- h-GEMM: per-iter rotated chase, depth-3 A / depth-2 B prefetch
        if (lev > 0) {
            const int* colPrev = colCnt + (lev - 1) * NTILE;
            const int it0 = ntile >> 1;   // rotated start iter (pair == iter)
            uint_t pmask = 0;

            const uint_t* aBaseH[2];
#pragma unroll
            for (int m = 0; m < 2; ++m) {
                int p = s_par[wr * 32 + m * 16 + l15];
                aBaseH[m] = hPack + (size_t)((p > 0) ? (p - 1) : 0) * DIM;
            }

#define ITQ(s) ((it0 + (s)) & 15)
            uint4 ha[3][2][2]; uint4 hb[2][2];
            GATEI(colPrev, nPrev, ITQ(0), 2);
            LDA_H(ha[0], ITQ(0)); LDB(hb[0], tbh, ITQ(0));
            GATEI(colPrev, nPrev, ITQ(1), 1);
            LDA_H(ha[1], ITQ(1)); LDB(hb[1], tbh, ITQ(1));
            GATEI(colPrev, nPrev, ITQ(2), 1);
            LDA_H(ha[2], ITQ(2));
#pragma unroll
            for (int s = 0; s < 16; ++s) {
                __builtin_amdgcn_s_setprio(1);
                COMP_H(ha[s % 3], hb[s & 1]);
                __builtin_amdgcn_s_setprio(0);
                if (s + 3 < 16) {
                    GATEI(colPrev, nPrev, ITQ(s + 3), 1);
                    LDA_H(ha[s % 3], ITQ(s + 3));
                }
                if (s + 2 < 16) { LDB(hb[s & 1], tbh, ITQ(s + 2)); }
            }
#undef ITQ
        }

        // ---- wide single-pass epilogue: thread -> (row, dl-pair) ----
        int cntloc = cnt - r0; if (cntloc > BM) cntloc = BM;
        int erow = tid >> 3, qd = tid & 7;     // row 0..63, pair-of-dims 0..7
        int dbase = (jc >> 3) + qd * 2;        // u32-granular d index

        // (0) gate c-ready of own ntile (prev level), then gather cPack
        if (lev > 0) {
            const int* cPrev = cCnt + (lev - 1) * NTILE;
            while (__hip_atomic_load(&cPrev[ntile], __ATOMIC_RELAXED,
                                     __HIP_MEMORY_SCOPE_AGENT) < nPrev)
                __builtin_amdgcn_s_sleep(1);
            asm volatile("" ::: "memory");
        }
        float CPv[2];
        {
            int p = (erow < cntloc) ? s_par[erow] : 0;
            uint2 cw = make_uint2(0u, 0u);
            if (p > 0) cw = *(const uint2*)(cPack + (size_t)(p - 1) * DIM + dbase);
            CPv[0] = unpackw(cw.x); CPv[1] = unpackw(cw.y);
        }

        // (2) full transpose (each wave its own 32x32 sub-block; disjoint)
#pragma unroll
        for (int m = 0; m < 2; ++m)
#pragma unroll
            for (int n = 0; n < 2; ++n) {
                int row = wr * 32 + m * 16 + g * 4;
                int c = wq * 32 + n * 16 + l15;
#pragma unroll
                for (int r = 0; r < 4; ++r) eps[(row + r) * 132 + c] = acc[m][n][r];
            }
        __syncthreads();

        // (3) LSTM cell: 2 consecutive dims per thread
        float cn2[2], hn2[2];
        int enode = -1;
        if (erow < cntloc) {
            enode = s_node[erow];
            const float* ep = &eps[erow * 132 + qd * 16];
            float tm0 = s_tm[erow][0], tm1 = s_tm[erow][1];
#pragma unroll
            for (int j = 0; j < 2; ++j) {
                float4 v0 = *(const float4*)(ep + j * 8);
                float4 v1 = *(const float4*)(ep + j * 8 + 4);
                int jb = jc + (qd * 2 + j) * 8;
                float4 b0 = *(const float4*)(bias + jb);
                float4 b1 = *(const float4*)(bias + jb + 4);
                float cp = CPv[j];
                float cv = sigm(v0.x + b0.x) * tanh_fast(v0.z + b0.z)
                         + sigm(v0.w + b0.w) * cp;
                float hv = sigm(v0.y + b0.y) * tanh_fast(cv);
                float cl = sigm(v1.x + b1.x) * tanh_fast(v1.z + b1.z)
                         + sigm(v1.w + b1.w) * cp;
                float hl = sigm(v1.y + b1.y) * tanh_fast(cl);
                cn2[j] = tm0 * cl + tm1 * cv;
                hn2[j] = tm0 * hl + tm1 * hv;
            }
            // publish h FIRST (children's h-GEMM needs only this)
            size_t oi = (size_t)enode * DIM + dbase;
            u64_t h01 = (u64_t)packf(hn2[0]) | ((u64_t)packf(hn2[1]) << 32);
            __hip_atomic_store((u64_t*)(hPack + oi), h01,
                               __ATOMIC_RELAXED, __HIP_MEMORY_SCOPE_AGENT);
        }

        // (4) drain h stores, publish h-ready
        __builtin_amdgcn_s_waitcnt(0);
        __syncthreads();
        if (tid == 0)
            __hip_atomic_fetch_add(&colCnt[lev * NTILE + ntile], 1,
                                   __ATOMIC_RELAXED, __HIP_MEMORY_SCOPE_AGENT);

        // (5) store c + plain outputs, drain, publish c-ready
        if (enode >= 0) {
            size_t oi = (size_t)enode * DIM + dbase;
            u64_t c01 = (u64_t)packf(cn2[0]) | ((u64_t)packf(cn2[1]) << 32);
            __hip_atomic_store((u64_t*)(cPack + oi), c01,
                               __ATOMIC_RELAXED, __HIP_MEMORY_SCOPE_AGENT);
            *(float2*)(cOut + oi) = make_float2(cn2[0], cn2[1]);
            *(float2*)(hOut + oi) = make_float2(hn2[0], hn2[1]);
        }
        __builtin_amdgcn_s_waitcnt(0);
        __syncthreads();
        if (tid == 0)
            __hip_atomic_fetch_add(&cCnt[lev * NTILE + ntile], 1,
                                   __ATOMIC_RELAXED, __HIP_MEMORY_SCOPE_AGENT);
        __syncthreads();   // protect s_node/s_par before next tile overwrites
    }
#undef LDB
#undef LDA_H
#undef LDA_X
#undef COMP_H
#undef COMP_X
#undef POLL16
#undef GATEI
}

// ---------------------------------------------------------------------------
extern "C" void kernel_launch(void* const* d_in, const int* in_sizes, int n_in,
                              void* d_out, int out_size, void* d_ws, size_t ws_size,
                              hipStream_t stream) {
    const float* inputs      = (const float*)d_in[0];
    const float* type_mask   = (const float*)d_in[1];
    const int*   parent      = (const int*)d_in[2];
    const float* W_ioux_vis  = (const float*)d_in[3];
    const float* b_ioux_vis  = (const float*)d_in[4];
    const float* W_iouh_vis  = (const float*)d_in[5];
    const float* b_iouh_vis  = (const float*)d_in[6];
    const float* W_fx_vis    = (const float*)d_in[7];
    const float* b_fx_vis    = (const float*)d_in[8];
    const float* W_fh_vis    = (const float*)d_in[9];
    const float* b_fh_vis    = (const float*)d_in[10];
    const float* W_ioux_lang = (const float*)d_in[11];
    const float* b_ioux_lang = (const float*)d_in[12];
    const float* W_iouh_lang = (const float*)d_in[13];
    const float* b_iouh_lang = (const float*)d_in[14];
    const float* W_fx_lang   = (const float*)d_in[15];
    const float* b_fx_lang   = (const float*)d_in[16];
    const float* W_fh_lang   = (const float*)d_in[17];
    const float* b_fh_lang   = (const float*)d_in[18];

    ushort_t* Wimg = (ushort_t*)d_ws;                      // 8 MB
    float* bias    = (float*)(Wimg + WIMG_USHORTS);
    int* order     = (int*)(bias + NCOLS);
    int* offsets   = order + N_NODES;
    int* counts    = offsets + (N_NODES + 2);
    int* cursors   = counts + (N_NODES + 2);
    int* nlev      = cursors + (N_NODES + 2);
    int* tilestart = nlev + 8;
    int* rbStart   = tilestart + (N_NODES + 2);
    int* colCnt    = rbStart + (N_NODES + 2);              // 4096
    int* cCnt      = colCnt + MAXLEV_LDS * NTILE;          // 4096
    size_t off2 = (size_t)((char*)(cCnt + MAXLEV_LDS * NTILE) - (char*)d_ws);
    off2 = (off2 + 255) & ~(size_t)255;
    uint_t* hPack = (uint_t*)((char*)d_ws + off2);                       // 16 MB
    uint_t* cPack = hPack + (size_t)N_NODES * DIM;                       // 16 MB

    float* out = (float*)d_out;

    hipMemsetAsync((void*)colCnt, 0, 2 * MAXLEV_LDS * NTILE * sizeof(int), stream);

    hipLaunchKernelGGL(prep_wimg_kernel, dim3(NTILE * KIT), dim3(256), 0, stream,
                       W_ioux_vis, W_iouh_vis, W_fx_vis, W_fh_vis,
                       W_ioux_lang, W_iouh_lang, W_fx_lang, W_fh_lang, Wimg);
    hipLaunchKernelGGL(prep_bias_kernel, dim3(NCOLS / 256), dim3(256), 0, stream,
                       b_ioux_vis, b_iouh_vis, b_fx_vis, b_fh_vis,
                       b_ioux_lang, b_iouh_lang, b_fx_lang, b_fh_lang, bias);
    hipLaunchKernelGGL(levels_sort_kernel, dim3(1), dim3(1024), 0, stream,
                       parent, order, offsets, counts, cursors, nlev, tilestart,
                       rbStart);

    int occ = 0;
    if (hipOccupancyMaxActiveBlocksPerMultiprocessor(&occ, (const void*)tree_fused_kernel, 512, 0) != hipSuccess || occ < 1)
        occ = 1;
    int bpc = occ < 2 ? occ : 2;
    dim3 grid(256 * bpc);

    void* args[] = { (void*)&inputs, (void*)&type_mask, (void*)&Wimg, (void*)&bias,
                     (void*)&order, (void*)&offsets, (void*)&nlev, (void*)&parent,
                     (void*)&rbStart, (void*)&colCnt, (void*)&cCnt,
                     (void*)&hPack, (void*)&cPack, (void*)&out };
    hipLaunchCooperativeKernel((const void*)tree_fused_kernel, grid, dim3(512), args, 0, stream);
}

// Round 17
// 741.504 us; speedup vs baseline: 1.3476x; 1.3476x over previous
//
#include <hip/hip_runtime.h>
#include <math.h>

typedef unsigned short ushort_t;
typedef unsigned int uint_t;
typedef unsigned long long u64_t;
typedef __attribute__((ext_vector_type(8))) short short8;
typedef __attribute__((ext_vector_type(4))) float f32x4;

#define N_NODES 8192
#define DIM 512
#define KTOT 1024
#define NCOLS 4096
#define BM 128
#define BN 128
#define NTILE (NCOLS / BN)   // 32 column tiles
#define KIT (KTOT / 32)      // 32 k iterations (BK=32)
#define WIMG_USHORTS ((size_t)NTILE * KIT * 4096)
#define MAXLEV_LDS 128
#define CSTRIDE 32           // ints per counter (one 128B line each)

__device__ __forceinline__ float sigm(float x) { return 1.0f / (1.0f + __expf(-x)); }
__device__ __forceinline__ float tanh_fast(float x) {
    float ax = fabsf(x);
    float e = __expf(2.0f * ax);
    float t = 1.0f - 2.0f / (e + 1.0f);
    return copysignf(t, x);
}
__device__ __forceinline__ uint_t packf(float f) {
    uint_t u = __float_as_uint(f);
    uint_t hi = u & 0xffff0000u;
    float r = f - __uint_as_float(hi);
    return hi | (__float_as_uint(r) >> 16);
}
__device__ __forceinline__ float unpackw(uint_t w) {
    return __uint_as_float(w & 0xffff0000u) + __uint_as_float(w << 16);
}
__device__ __forceinline__ uint_t rne16(float f) {
    uint_t u = __float_as_uint(f);
    return (u + 0x7fffu + ((u >> 16) & 1u)) >> 16;
}

// split 8 packed (hi|lo) u32 -> hi-frag / lo-frag short8
__device__ __forceinline__ void fragAB_u32(const uint4 w0, const uint4 w1,
                                           short8& hi8, short8& lo8) {
    union { uint_t w[4]; short8 s; } H, L;
    uint_t u[8] = { w0.x, w0.y, w0.z, w0.w, w1.x, w1.y, w1.z, w1.w };
#pragma unroll
    for (int j = 0; j < 4; ++j) {
        H.w[j] = (u[2 * j + 1] & 0xffff0000u) | (u[2 * j] >> 16);
        L.w[j] = (u[2 * j + 1] << 16) | (u[2 * j] & 0xffffu);
    }
    hi8 = H.s; lo8 = L.s;
}

// split 8 fp32 -> hi-frag (trunc) / lo-frag (residual) short8
__device__ __forceinline__ void fragA_f32(const float4 f0, const float4 f1,
                                          short8& hi8, short8& lo8) {
    union { uint_t w[4]; short8 s; } H, L;
    float f[8] = { f0.x, f0.y, f0.z, f0.w, f1.x, f1.y, f1.z, f1.w };
#pragma unroll
    for (int j = 0; j < 4; ++j) {
        float a = f[2 * j], b = f[2 * j + 1];
        uint_t h0 = __float_as_uint(a) & 0xffff0000u;
        uint_t h1 = __float_as_uint(b) & 0xffff0000u;
        float r0 = a - __uint_as_float(h0);
        float r1 = b - __uint_as_float(h1);
        H.w[j] = h1 | (h0 >> 16);
        L.w[j] = (__float_as_uint(r1) & 0xffff0000u) | (__float_as_uint(r0) >> 16);
    }
    hi8 = H.s; lo8 = L.s;
}

// ---------------------------------------------------------------------------
// Prep: weights -> bf16 (hi plane, RNE), direct-fragment image (verified r8-r16)
// ---------------------------------------------------------------------------
__global__ void __launch_bounds__(256) prep_wimg_kernel(
    const float* __restrict__ Wx_iou_v, const float* __restrict__ Wh_iou_v,
    const float* __restrict__ Wx_f_v,   const float* __restrict__ Wh_f_v,
    const float* __restrict__ Wx_iou_l, const float* __restrict__ Wh_iou_l,
    const float* __restrict__ Wx_f_l,   const float* __restrict__ Wh_f_l,
    ushort_t* __restrict__ Wimg)
{
    __shared__ float T[32][132];   // T[kk][jloc]
    int p = blockIdx.x >> 5, it = blockIdx.x & 31;
    int tid = threadIdx.x;
#pragma unroll
    for (int e = 0; e < 16; ++e) {
        int lin = e * 256 + tid;
        int dloc = lin & 15, kk = (lin >> 4) & 31, q = lin >> 9;
        int d = p * 16 + dloc;
        int qq = q & 3; bool lang = q >= 4;
        int k = it * 32 + kk;
        const float* W; int col, stride;
        if (qq < 3) { col = qq * DIM + d; stride = 3 * DIM;
            W = (k < DIM) ? (lang ? Wx_iou_l : Wx_iou_v) : (lang ? Wh_iou_l : Wh_iou_v); }
        else        { col = d; stride = DIM;
            W = (k < DIM) ? (lang ? Wx_f_l : Wx_f_v) : (lang ? Wh_f_l : Wh_f_v); }
        int kr = (k < DIM) ? k : (k - DIM);
        T[kk][dloc * 8 + q] = W[(size_t)kr * stride + col];
    }
    __syncthreads();
    size_t tilebase = (size_t)blockIdx.x * 4096;
#pragma unroll
    for (int gch = 0; gch < 2; ++gch) {
        int gi = gch * 256 + tid;          // uint4 index 0..511
        int col = gi >> 2, gd = gi & 3;
        uint_t wds[4];
#pragma unroll
        for (int i = 0; i < 4; ++i) {
            uint_t v0 = rne16(T[gd * 8 + 2 * i][col]);
            uint_t v1 = rne16(T[gd * 8 + 2 * i + 1][col]);
            wds[i] = (v1 << 16) | v0;
        }
        *(uint4*)(Wimg + tilebase + (size_t)gi * 8) = make_uint4(wds[0], wds[1], wds[2], wds[3]);
    }
}

__global__ void prep_bias_kernel(
    const float* __restrict__ bx_iou_v, const float* __restrict__ bh_iou_v,
    const float* __restrict__ bx_f_v,   const float* __restrict__ bh_f_v,
    const float* __restrict__ bx_iou_l, const float* __restrict__ bh_iou_l,
    const float* __restrict__ bx_f_l,   const float* __restrict__ bh_f_l,
    float* __restrict__ bias)
{
    int j = blockIdx.x * blockDim.x + threadIdx.x;
    if (j >= NCOLS) return;
    int d = j >> 3, q = j & 7;
    int qq = q & 3;
    bool lang = (q & 4) != 0;
    const float* bx; const float* bh; int col;
    if (qq < 3) { col = qq * DIM + d; bx = lang ? bx_iou_l : bx_iou_v; bh = lang ? bh_iou_l : bh_iou_v; }
    else        { col = d;            bx = lang ? bx_f_l  : bx_f_v;   bh = lang ? bh_f_l  : bh_f_v; }
    bias[j] = bx[col] + bh[col];
}

// ---------------------------------------------------------------------------
// Level computation + counting sort + rowblock tables (verified r4-r16)
// ---------------------------------------------------------------------------
__global__ void __launch_bounds__(1024) levels_sort_kernel(
    const int* __restrict__ parent,
    int* __restrict__ order, int* __restrict__ offsets,
    int* __restrict__ counts, int* __restrict__ cursors,
    int* __restrict__ nlev, int* __restrict__ tilestart,
    int* __restrict__ rbStart)
{
    __shared__ int s_level[N_NODES];
    __shared__ int s_assigned;
    __shared__ int s_maxlev;
    int tid = threadIdx.x;
    int pr[8];
#pragma unroll
    for (int ii = 0; ii < 8; ++ii) {
        int i = tid + ii * 1024;
        pr[ii] = parent[i];
        s_level[i] = -1;
    }
    for (int i = tid; i <= N_NODES; i += 1024) counts[i] = 0;
    if (tid == 0) { s_assigned = 0; s_maxlev = 0; }
    __syncthreads();

    for (int pass = 0; pass <= N_NODES; ++pass) {
        int newly = 0;
#pragma unroll
        for (int ii = 0; ii < 8; ++ii) {
            int i = tid + ii * 1024;
            if (s_level[i] < 0) {
                int p = pr[ii];
                if (p == 0) { s_level[i] = 0; newly++; }
                else { int lp = s_level[p - 1]; if (lp >= 0) { s_level[i] = lp + 1; newly++; } }
            }
        }
        if (newly) atomicAdd(&s_assigned, newly);
        __syncthreads();
        int a = s_assigned;
        if (a >= N_NODES) break;
        __syncthreads();
    }

#pragma unroll
    for (int ii = 0; ii < 8; ++ii) {
        int i = tid + ii * 1024;
        int lv = s_level[i];
        atomicAdd(&counts[lv], 1);
        atomicMax(&s_maxlev, lv);
    }
    __syncthreads();
    if (tid == 0) {
        int nl = s_maxlev + 1;
        nlev[0] = nl;
        int off = 0, toff = 0, rb = 0;
        for (int l = 0; l < nl; ++l) {
            offsets[l] = off; cursors[l] = off;
            tilestart[l] = toff; rbStart[l] = rb;
            int mt = (counts[l] + BM - 1) / BM;
            rb += mt;
            toff += mt * NTILE;
            off += counts[l];
        }
        offsets[nl] = off;
        tilestart[nl] = toff;
        rbStart[nl] = rb;
        nlev[1] = toff;   // total fused tiles
    }
    __syncthreads();
#pragma unroll
    for (int ii = 0; ii < 8; ++ii) {
        int i = tid + ii * 1024;
        int pos = atomicAdd(&cursors[s_level[i]], 1);
        order[pos] = i;
    }
}

// ---------------------------------------------------------------------------
// Fused worker (r14 base): 8 waves, one-round-poll gates on LINE-PADDED
// counters, rotated chase, wide u64/float4 epilogue, fence-free sc1 dataflow.
// ---------------------------------------------------------------------------
__global__ void __launch_bounds__(512, 2) tree_fused_kernel(
    const float* __restrict__ inputs, const float* __restrict__ type_mask,
    const ushort_t* __restrict__ Wimg, const float* __restrict__ bias,
    const int* __restrict__ order, const int* __restrict__ offsets,
    const int* __restrict__ nlev, const int* __restrict__ parent,
    const int* __restrict__ rbStart,
    int* __restrict__ colCnt,
    uint_t* __restrict__ hPack, uint_t* __restrict__ cPack,
    float* __restrict__ out)
{
    float* cOut = out;
    float* hOut = out + (size_t)N_NODES * DIM;

    __shared__ float eps[BM * 132];      // 67.6 KB single-pass transpose
    __shared__ int s_node[BM];
    __shared__ int s_par[BM];
    __shared__ float s_tm[BM][2];
    __shared__ int s_rbs[MAXLEV_LDS];
    __shared__ int s_off[MAXLEV_LDS];

    int tid = threadIdx.x;
    int lane = tid & 63, w = tid >> 6;        // w in 0..7
    int wr = w >> 1, wc = w & 1;              // 4 row groups x 2 col halves
    int l15 = lane & 15, g = lane >> 4;
    int nl = nlev[0];
    int total = nlev[1];

    int nload = nl + 1; if (nload > MAXLEV_LDS) nload = MAXLEV_LDS;
    for (int i = tid; i < nload; i += 512) { s_rbs[i] = rbStart[i]; s_off[i] = offsets[i]; }
    __syncthreads();

    // B fragment base: cols wc*64 + n*16 + l15 (n<4), granule g
    const ushort_t* bLane = Wimg + (size_t)(wc * 64 + l15) * 32 + (size_t)g * 8;

#define LDB(RB, tilebase, itt) { \
    _Pragma("unroll") for (int n_ = 0; n_ < 4; ++n_) \
        RB[n_] = *(const uint4*)(bLane + (size_t)(tilebase + (itt)) * 4096 + n_ * 512); }

#define LDA_H(RA, itrel) { \
    _Pragma("unroll") for (int m_ = 0; m_ < 2; ++m_) { \
        const uint4* p_ = (const uint4*)(aBaseH[m_] + (itrel) * 32 + g * 8); \
        RA[m_][0] = p_[0]; RA[m_][1] = p_[1]; } }

#define LDA_X(RA, itt) { \
    _Pragma("unroll") for (int m_ = 0; m_ < 2; ++m_) { \
        const float4* p_ = (const float4*)(aBaseX[m_] + (itt) * 32 + g * 8); \
        RA[m_][0] = p_[0]; RA[m_][1] = p_[1]; } }

#define COMP_H(RA, RB) { \
    short8 bh_[4]; \
    _Pragma("unroll") for (int n_ = 0; n_ < 4; ++n_) { \
        union { uint4 u; short8 s; } c_; c_.u = RB[n_]; bh_[n_] = c_.s; } \
    _Pragma("unroll") for (int m_ = 0; m_ < 2; ++m_) { \
        short8 ah_, al_; fragAB_u32(RA[m_][0], RA[m_][1], ah_, al_); \
        _Pragma("unroll") for (int n_ = 0; n_ < 4; ++n_) { \
            acc[m_][n_] = __builtin_amdgcn_mfma_f32_16x16x32_bf16(ah_, bh_[n_], acc[m_][n_], 0, 0, 0); \
            acc[m_][n_] = __builtin_amdgcn_mfma_f32_16x16x32_bf16(al_, bh_[n_], acc[m_][n_], 0, 0, 0); } } }

#define COMP_X(RA, RB) { \
    short8 bh_[4]; \
    _Pragma("unroll") for (int n_ = 0; n_ < 4; ++n_) { \
        union { uint4 u; short8 s; } c_; c_.u = RB[n_]; bh_[n_] = c_.s; } \
    _Pragma("unroll") for (int m_ = 0; m_ < 2; ++m_) { \
        short8 ah_, al_; fragA_f32(RA[m_][0], RA[m_][1], ah_, al_); \
        _Pragma("unroll") for (int n_ = 0; n_ < 4; ++n_) { \
            acc[m_][n_] = __builtin_amdgcn_mfma_f32_16x16x32_bf16(ah_, bh_[n_], acc[m_][n_], 0, 0, 0); \
            acc[m_][n_] = __builtin_amdgcn_mfma_f32_16x16x32_bf16(al_, bh_[n_], acc[m_][n_], 0, 0, 0); } } }

// one-round poll of ALL 32 prev-level columns (PADDED lines) -> group mask
#define POLL_ALL(colPrev, nPrev) { \
    int ok_ = 1; \
    if (lane < 32) { \
        int c_ = __hip_atomic_load(&(colPrev)[lane * CSTRIDE], __ATOMIC_RELAXED, \
                                   __HIP_MEMORY_SCOPE_AGENT); \
        ok_ = (c_ >= (nPrev)) ? 1 : 0; \
    } \
    uint_t cm_ = (uint_t)(__ballot(ok_) & 0xffffffffu); \
    uint_t gr_ = cm_ & (cm_ >> 1) & (cm_ >> 2) & (cm_ >> 3); \
    gmask = 0; \
    _Pragma("unroll") for (int g_ = 0; g_ < 8; ++g_) \
        gmask |= ((gr_ >> (4 * g_)) & 1u) << g_; }

// per-wave gate on group gq; memoized via gmask; one poll covers all groups
#define WAVE_GATE(colPrev, nPrev, gq, slp) { \
    if (!(gmask & (1u << (gq)))) { \
        for (;;) { \
            POLL_ALL(colPrev, nPrev); \
            if (gmask & (1u << (gq))) break; \
            __builtin_amdgcn_s_sleep(slp); \
        } \
        asm volatile("" ::: "memory"); \
    } }

    for (int t = blockIdx.x; t < total; t += gridDim.x) {
        // locate tile in level-ordered list
        int lev = 0;
        while (lev + 1 < nload && s_rbs[lev + 1] * NTILE <= t) ++lev;
        int lt = t - s_rbs[lev] * NTILE;
        int ntile = lt % NTILE;
        int mt = lt / NTILE;
        int start = s_off[lev];
        int cnt = s_off[lev + 1] - start;
        int jc = ntile * BN;
        int r0 = mt * BM;
        int tbx = ntile * KIT;        // Wimg x half: it 0..15
        int tbh = ntile * KIT + 16;   // Wimg h half: it 16..31

        if (tid < BM) {
            int r = r0 + tid;
            int node = (r < cnt) ? order[start + r] : -1;
            s_node[tid] = node;
            int p = (node >= 0) ? parent[node] : 0;
            s_par[tid] = p;
            float t0 = 0.f, t1 = 0.f;
            if (node >= 0) { t0 = type_mask[node * 2]; t1 = type_mask[node * 2 + 1]; }
            s_tm[tid][0] = t0; s_tm[tid][1] = t1;
        }
        __syncthreads();

        f32x4 acc[2][4];
#pragma unroll
        for (int m = 0; m < 2; ++m)
#pragma unroll
            for (int n = 0; n < 4; ++n) acc[m][n] = (f32x4)(0.f);

        // ---- x-GEMM (no dependencies): gathered input rows
        {
            const float* aBaseX[2];
#pragma unroll
            for (int m = 0; m < 2; ++m) {
                int nd = s_node[wr * 32 + m * 16 + l15];
                aBaseX[m] = inputs + (size_t)(nd < 0 ? 0 : nd) * DIM;
            }
            float4 xa0[2][2], xa1[2][2]; uint4 xb0[4], xb1[4];
            LDA_X(xa0, 0); LDB(xb0, tbx, 0);
            LDA_X(xa1, 1); LDB(xb1, tbx, 1);
#pragma unroll
            for (int ii = 0; ii < 8; ++ii) {
                int e = 2 * ii, o = e + 1;
                __builtin_amdgcn_s_setprio(1);
                COMP_X(xa0, xb0);
                __builtin_amdgcn_s_setprio(0);
                if (e + 2 < 16) { LDA_X(xa0, e + 2); LDB(xb0, tbx, e + 2); }
                __builtin_amdgcn_s_setprio(1);
                COMP_X(xa1, xb1);
                __builtin_amdgcn_s_setprio(0);
                if (o + 2 < 16) { LDA_X(xa1, o + 2); LDB(xb1, tbx, o + 2); }
            }
        }

        // ---- h-GEMM: rotated per-wave chase, one-round-poll padded gates
        if (lev > 0) {
            const int* colPrev = colCnt + (size_t)(lev - 1) * NTILE * CSTRIDE;
            int nPrev = s_rbs[lev] - s_rbs[lev - 1];
            const int gb = ntile >> 2;   // rotated start group
            uint_t gmask = 0;

            const uint_t* aBaseH[2];
#pragma unroll
            for (int m = 0; m < 2; ++m) {
                int p = s_par[wr * 32 + m * 16 + l15];
                aBaseH[m] = hPack + (size_t)((p > 0) ? (p - 1) : 0) * DIM;
            }

            uint4 ha0[2][2], ha1[2][2]; uint4 hb0[4], hb1[4];
            WAVE_GATE(colPrev, nPrev, gb, 4);
            LDA_H(ha0, 2 * gb); LDB(hb0, tbh, 2 * gb);
            LDA_H(ha1, 2 * gb + 1); LDB(hb1, tbh, 2 * gb + 1);
#pragma unroll
            for (int s = 0; s < 8; ++s) {
                const int gn = (gb + s + 1) & 7;
                __builtin_amdgcn_s_setprio(1);
                COMP_H(ha0, hb0);
                __builtin_amdgcn_s_setprio(0);
                if (s < 7) {
                    WAVE_GATE(colPrev, nPrev, gn, 2);
                    LDA_H(ha0, 2 * gn); LDB(hb0, tbh, 2 * gn);
                }
                __builtin_amdgcn_s_setprio(1);
                COMP_H(ha1, hb1);
                __builtin_amdgcn_s_setprio(0);
                if (s < 7) { LDA_H(ha1, 2 * gn + 1); LDB(hb1, tbh, 2 * gn + 1); }
            }
        }

        // ---- wide single-pass epilogue: thread -> (row, dl-quad) ----
        int cntloc = cnt - r0; if (cntloc > BM) cntloc = BM;
        int erow = tid >> 2, qd = tid & 3;     // row 0..127, quad 0..3
        int dbase = (jc >> 3) + qd * 4;        // u32-granular d index

        // (1) early cPack gather (all parent cols gated in k-loop); uint4
        float CPv[4];
        {
            int p = (erow < cntloc) ? s_par[erow] : 0;
            uint4 cw = make_uint4(0u, 0u, 0u, 0u);
            if (p > 0) cw = *(const uint4*)(cPack + (size_t)(p - 1) * DIM + dbase);
            CPv[0] = unpackw(cw.x); CPv[1] = unpackw(cw.y);
            CPv[2] = unpackw(cw.z); CPv[3] = unpackw(cw.w);
        }

        // (2) full transpose (each wave its own sub-block; disjoint writes)
#pragma unroll
        for (int m = 0; m < 2; ++m)
#pragma unroll
            for (int n = 0; n < 4; ++n) {
                int row = wr * 32 + m * 16 + g * 4;
                int c = wc * 64 + n * 16 + l15;
#pragma unroll
                for (int r = 0; r < 4; ++r) eps[(row + r) * 132 + c] = acc[m][n][r];
            }
        __syncthreads();

        // (3) LSTM cell: 4 consecutive dims per thread; u64 sc1 publish
        float cn4[4], hn4[4];
        int enode = -1;
        if (erow < cntloc) {
            enode = s_node[erow];
            const float* ep = &eps[erow * 132 + qd * 32];
            float tm0 = s_tm[erow][0], tm1 = s_tm[erow][1];
            float cpl[4] = { CPv[0], CPv[1], CPv[2], CPv[3] };
#pragma unroll
            for (int j = 0; j < 4; ++j) {
                float4 v0 = *(const float4*)(ep + j * 8);
                float4 v1 = *(const float4*)(ep + j * 8 + 4);
                int jb = jc + (qd * 4 + j) * 8;
                float4 b0 = *(const float4*)(bias + jb);
                float4 b1 = *(const float4*)(bias + jb + 4);
                float cp = cpl[j];
                float cv = sigm(v0.x + b0.x) * tanh_fast(v0.z + b0.z)
                         + sigm(v0.w + b0.w) * cp;
                float hv = sigm(v0.y + b0.y) * tanh_fast(cv);
                float cl = sigm(v1.x + b1.x) * tanh_fast(v1.z + b1.z)
                         + sigm(v1.w + b1.w) * cp;
                float hl = sigm(v1.y + b1.y) * tanh_fast(cl);
                cn4[j] = tm0 * cl + tm1 * cv;
                hn4[j] = tm0 * hl + tm1 * hv;
            }
            size_t oi = (size_t)enode * DIM + dbase;
            u64_t c01 = (u64_t)packf(cn4[0]) | ((u64_t)packf(cn4[1]) << 32);
            u64_t c23 = (u64_t)packf(cn4[2]) | ((u64_t)packf(cn4[3]) << 32);
            u64_t h01 = (u64_t)packf(hn4[0]) | ((u64_t)packf(hn4[1]) << 32);
            u64_t h23 = (u64_t)packf(hn4[2]) | ((u64_t)packf(hn4[3]) << 32);
            u64_t* cdst = (u64_t*)(cPack + oi);
            u64_t* hdst = (u64_t*)(hPack + oi);
            __hip_atomic_store(cdst,     c01, __ATOMIC_RELAXED, __HIP_MEMORY_SCOPE_AGENT);
            __hip_atomic_store(cdst + 1, c23, __ATOMIC_RELAXED, __HIP_MEMORY_SCOPE_AGENT);
            __hip_atomic_store(hdst,     h01, __ATOMIC_RELAXED, __HIP_MEMORY_SCOPE_AGENT);
            __hip_atomic_store(hdst + 1, h23, __ATOMIC_RELAXED, __HIP_MEMORY_SCOPE_AGENT);
        }

        // (4) drain sc1 stores, publish (padded line), THEN plain outputs
        __builtin_amdgcn_s_waitcnt(0);
        __syncthreads();
        if (tid == 0)
            __hip_atomic_fetch_add(&colCnt[(size_t)(lev * NTILE + ntile) * CSTRIDE], 1,
                                   __ATOMIC_RELAXED, __HIP_MEMORY_SCOPE_AGENT);

        if (enode >= 0) {
            size_t oi = (size_t)enode * DIM + dbase;
            *(float4*)(cOut + oi) = make_float4(cn4[0], cn4[1], cn4[2], cn4[3]);
            *(float4*)(hOut + oi) = make_float4(hn4[0], hn4[1], hn4[2], hn4[3]);
        }
        __syncthreads();   // protect s_node/s_par before next tile overwrites
    }
#undef LDB
#undef LDA_H
#undef LDA_X
#undef COMP_H
#undef COMP_X
#undef POLL_ALL
#undef WAVE_GATE
}

// ---------------------------------------------------------------------------
extern "C" void kernel_launch(void* const* d_in, const int* in_sizes, int n_in,
                              void* d_out, int out_size, void* d_ws, size_t ws_size,
                              hipStream_t stream) {
    const float* inputs      = (const float*)d_in[0];
    const float* type_mask   = (const float*)d_in[1];
    const int*   parent      = (const int*)d_in[2];
    const float* W_ioux_vis  = (const float*)d_in[3];
    const float* b_ioux_vis  = (const float*)d_in[4];
    const float* W_iouh_vis  = (const float*)d_in[5];
    const float* b_iouh_vis  = (const float*)d_in[6];
    const float* W_fx_vis    = (const float*)d_in[7];
    const float* b_fx_vis    = (const float*)d_in[8];
    const float* W_fh_vis    = (const float*)d_in[9];
    const float* b_fh_vis    = (const float*)d_in[10];
    const float* W_ioux_lang = (const float*)d_in[11];
    const float* b_ioux_lang = (const float*)d_in[12];
    const float* W_iouh_lang = (const float*)d_in[13];
    const float* b_iouh_lang = (const float*)d_in[14];
    const float* W_fx_lang   = (const float*)d_in[15];
    const float* b_fx_lang   = (const float*)d_in[16];
    const float* W_fh_lang   = (const float*)d_in[17];
    const float* b_fh_lang   = (const float*)d_in[18];

    ushort_t* Wimg = (ushort_t*)d_ws;                      // 8 MB
    float* bias    = (float*)(Wimg + WIMG_USHORTS);
    int* order     = (int*)(bias + NCOLS);
    int* offsets   = order + N_NODES;
    int* counts    = offsets + (N_NODES + 2);
    int* cursors   = counts + (N_NODES + 2);
    int* nlev      = cursors + (N_NODES + 2);
    int* tilestart = nlev + 8;
    int* rbStart   = tilestart + (N_NODES + 2);
    size_t cOff = (size_t)((char*)(rbStart + (N_NODES + 2)) - (char*)d_ws);
    cOff = (cOff + 127) & ~(size_t)127;
    int* colCnt = (int*)((char*)d_ws + cOff);              // 4096 lines = 512 KB
    size_t off2 = cOff + (size_t)MAXLEV_LDS * NTILE * CSTRIDE * sizeof(int);
    off2 = (off2 + 255) & ~(size_t)255;
    uint_t* hPack = (uint_t*)((char*)d_ws + off2);                       // 16 MB
    uint_t* cPack = hPack + (size_t)N_NODES * DIM;                       // 16 MB

    float* out = (float*)d_out;

    hipMemsetAsync((void*)colCnt, 0, (size_t)MAXLEV_LDS * NTILE * CSTRIDE * sizeof(int), stream);

    hipLaunchKernelGGL(prep_wimg_kernel, dim3(NTILE * KIT), dim3(256), 0, stream,
                       W_ioux_vis, W_iouh_vis, W_fx_vis, W_fh_vis,
                       W_ioux_lang, W_iouh_lang, W_fx_lang, W_fh_lang, Wimg);
    hipLaunchKernelGGL(prep_bias_kernel, dim3(NCOLS / 256), dim3(256), 0, stream,
                       b_ioux_vis, b_iouh_vis, b_fx_vis, b_fh_vis,
                       b_ioux_lang, b_iouh_lang, b_fx_lang, b_fh_lang, bias);
    hipLaunchKernelGGL(levels_sort_kernel, dim3(1), dim3(1024), 0, stream,
                       parent, order, offsets, counts, cursors, nlev, tilestart,
                       rbStart);

    int occ = 0;
    if (hipOccupancyMaxActiveBlocksPerMultiprocessor(&occ, (const void*)tree_fused_kernel, 512, 0) != hipSuccess || occ < 1)
        occ = 1;
    int bpc = occ < 2 ? occ : 2;
    dim3 grid(256 * bpc);

    void* args[] = { (void*)&inputs, (void*)&type_mask, (void*)&Wimg, (void*)&bias,
                     (void*)&order, (void*)&offsets, (void*)&nlev, (void*)&parent,
                     (void*)&rbStart, (void*)&colCnt,
                     (void*)&hPack, (void*)&cPack, (void*)&out };
    hipLaunchCooperativeKernel((const void*)tree_fused_kernel, grid, dim3(512), args, 0, stream);
}